// Round 10
// baseline (69.275 us; speedup 1.0000x reference)
//
#include <hip/hip_runtime.h>

#define CH   64
#define NTOT 4096
#define NB   4
#define L2E  1.44269504088896340736f

typedef short  short4v  __attribute__((ext_vector_type(4)));
typedef short  short8v  __attribute__((ext_vector_type(8)));
typedef float  floatx4  __attribute__((ext_vector_type(4)));

// packed f32x2 -> bf16x2 (RNE), 1 VALU instr
static __device__ __forceinline__ unsigned pk2bf(float lo, float hi) {
    unsigned r;
    asm("v_cvt_pk_bf16_f32 %0, %1, %2" : "=v"(r) : "v"(lo), "v"(hi));
    return r;
}

// 2^x via v_exp_f32 (avoids __exp2f glibc macro clash)
static __device__ __forceinline__ float ex2(float x) {
    return __builtin_amdgcn_exp2f(x);
}

// ---------------------------------------------------------------------------
// Kernel 1: QKV projection (fp32 compute) -> bf16 outputs
//   kT, qT : (B, N, C) bf16 (unscaled);  v : (B, C, N) bf16
// grid = B * 128 (32-position tiles), 256 threads
// ---------------------------------------------------------------------------
__global__ __launch_bounds__(256) void qkv_proj(
    const float* __restrict__ x,
    const float* __restrict__ Wk, const float* __restrict__ Wq,
    const float* __restrict__ Wv,
    short* __restrict__ kT, short* __restrict__ qT, short* __restrict__ vg)
{
    __shared__ __align__(16) float xs [64][36];
    __shared__ __align__(16) float wkT[64][68];
    __shared__ __align__(16) float wqT[64][68];
    __shared__ __align__(16) float wvT[64][68];

    const int tid = threadIdx.x;
    const int b  = blockIdx.x >> 7;
    const int n0 = (blockIdx.x & 127) * 32;
    const float* xb = x + (size_t)b * CH * NTOT;

    {   // x tile: 64 c x 32 n
        int c = tid >> 2, nn = (tid & 3) << 3;
        *(float4*)&xs[c][nn]     = *(const float4*)&xb[(size_t)c * NTOT + n0 + nn];
        *(float4*)&xs[c][nn + 4] = *(const float4*)&xb[(size_t)c * NTOT + n0 + nn + 4];
    }
    for (int i = tid; i < 64 * 64; i += 256) {
        int o = i >> 6, c = i & 63;
        wkT[c][o] = Wk[i];
        wqT[c][o] = Wq[i];
        wvT[c][o] = Wv[i];
    }
    __syncthreads();

    const int to = tid >> 4, tn = tid & 15;
    const int ob = to * 4, nb = tn * 2;
    float ak[4][2] = {}, aq[4][2] = {}, av[4][2] = {};

    for (int c = 0; c < 64; ++c) {
        float x0 = xs[c][nb], x1 = xs[c][nb + 1];
        float4 k4 = *(const float4*)&wkT[c][ob];
        float4 q4 = *(const float4*)&wqT[c][ob];
        float4 v4 = *(const float4*)&wvT[c][ob];
        float ka[4] = {k4.x, k4.y, k4.z, k4.w};
        float qa[4] = {q4.x, q4.y, q4.z, q4.w};
        float va[4] = {v4.x, v4.y, v4.z, v4.w};
        #pragma unroll
        for (int i = 0; i < 4; ++i) {
            ak[i][0] += ka[i] * x0;  ak[i][1] += ka[i] * x1;
            aq[i][0] += qa[i] * x0;  aq[i][1] += qa[i] * x1;
            av[i][0] += va[i] * x0;  av[i][1] += va[i] * x1;
        }
    }

    #pragma unroll
    for (int j = 0; j < 2; ++j) {
        size_t row = (size_t)(b << 12) + n0 + nb + j;
        uint2 kk, qq;
        kk.x = pk2bf(ak[0][j], ak[1][j]);
        kk.y = pk2bf(ak[2][j], ak[3][j]);
        qq.x = pk2bf(aq[0][j], aq[1][j]);
        qq.y = pk2bf(aq[2][j], aq[3][j]);
        *(uint2*)&kT[row * 64 + ob] = kk;
        *(uint2*)&qT[row * 64 + ob] = qq;
    }
    #pragma unroll
    for (int i = 0; i < 4; ++i)
        *(unsigned*)&vg[(((size_t)(b << 6) + ob + i) << 12) + n0 + nb] =
            pk2bf(av[i][0], av[i][1]);
}

// ---------------------------------------------------------------------------
// Kernel 2: flash-attention partial over a 1024-key chunk.
// grid = 1024 blocks, 256 threads = 4 waves. Scores in natural units;
// p = 2^(S*L2E - m*L2E) via fma+v_exp. Exact skip (THR=0) when max stable.
// ---------------------------------------------------------------------------
__global__ __launch_bounds__(256) void attn_partial(
    const short* __restrict__ kT, const short* __restrict__ qT,
    const short* __restrict__ vg,
    float* __restrict__ opart, float* __restrict__ mlpart)
{
    __shared__ __align__(16) short smem[18432];   // 36864 B

    const int tid = threadIdx.x;
    const int w  = tid >> 6;
    const int l  = tid & 63;
    const int g  = l >> 4;
    const int ln = l & 15;

    const int bid  = blockIdx.x;
    const int xcd  = bid & 7, grp = bid >> 3;
    const int bk   = (xcd << 1) | (grp >> 6);
    const int b    = bk >> 2;
    const int kc   = bk & 3;
    const int qblk = grp & 63;
    const int part = (b << 8) | (kc << 6) | qblk;
    const int n0   = qblk << 6;
    const int kbase = kc << 10;

    const short* kTb = kT + ((size_t)(b << 12) + n0) * 64;
    const short* qTb = qT + ((size_t)b << 12) * 64;
    const short* vb  = vg + ((size_t)(b << 6) << 12);

    short* const kTs = smem;
    short* const qS  = smem + 4608;
    short* const vS  = smem + 9216;
    short* const PsW = smem + 13824 + w * 1152;

    {
        int r0 = tid >> 3, c8 = (tid & 7) << 3;
        *(short8v*)&kTs[r0 * 72 + c8]        = *(const short8v*)&kTb[r0 * 64 + c8];
        *(short8v*)&kTs[(r0 + 32) * 72 + c8] = *(const short8v*)&kTb[(r0 + 32) * 64 + c8];
    }
    __syncthreads();

    short8v bS0 = *(const short8v*)&kTs[((w << 4) + ln) * 72 + (g << 3)];
    short8v bS1 = *(const short8v*)&kTs[((w << 4) + ln) * 72 + 32 + (g << 3)];

    float mrun = -1e30f;
    float lrun = 0.f;
    floatx4 acc_o[4];
    #pragma unroll
    for (int ct = 0; ct < 4; ++ct) acc_o[ct] = (floatx4){0.f, 0.f, 0.f, 0.f};

    const int i0 = tid, i1 = tid + 256;

    short8v pf[4];
    pf[0] = *(const short8v*)&qTb[(size_t)(kbase + (i0 >> 3)) * 64 + ((i0 & 7) << 3)];
    pf[1] = *(const short8v*)&qTb[(size_t)(kbase + (i1 >> 3)) * 64 + ((i1 & 7) << 3)];
    pf[2] = *(const short8v*)&vb[(size_t)(i0 >> 3) * 4096 + kbase + ((i0 & 7) << 3)];
    pf[3] = *(const short8v*)&vb[(size_t)(i1 >> 3) * 4096 + kbase + ((i1 & 7) << 3)];

    for (int t = 0; t < 16; ++t) {
        __syncthreads();
        *(short8v*)&qS[(i0 >> 3) * 72 + ((i0 & 7) << 3)] = pf[0];
        *(short8v*)&qS[(i1 >> 3) * 72 + ((i1 & 7) << 3)] = pf[1];
        *(short8v*)&vS[(i0 >> 3) * 72 + ((i0 & 7) << 3)] = pf[2];
        *(short8v*)&vS[(i1 >> 3) * 72 + ((i1 & 7) << 3)] = pf[3];
        __syncthreads();
        if (t < 15) {
            int m1 = kbase + ((t + 1) << 6);
            pf[0] = *(const short8v*)&qTb[(size_t)(m1 + (i0 >> 3)) * 64 + ((i0 & 7) << 3)];
            pf[1] = *(const short8v*)&qTb[(size_t)(m1 + (i1 >> 3)) * 64 + ((i1 & 7) << 3)];
            pf[2] = *(const short8v*)&vb[(size_t)(i0 >> 3) * 4096 + m1 + ((i0 & 7) << 3)];
            pf[3] = *(const short8v*)&vb[(size_t)(i1 >> 3) * 4096 + m1 + ((i1 & 7) << 3)];
        }

        // ---- S^T tile (natural units): A = keys (qS rows), B = queries ----
        floatx4 sacc[4];
        #pragma unroll
        for (int mt = 0; mt < 4; ++mt) {
            short8v a0 = *(const short8v*)&qS[((mt << 4) + ln) * 72 + (g << 3)];
            short8v a1 = *(const short8v*)&qS[((mt << 4) + ln) * 72 + 32 + (g << 3)];
            floatx4 acc = (floatx4){0.f, 0.f, 0.f, 0.f};
            acc = __builtin_amdgcn_mfma_f32_16x16x32_bf16(a0, bS0, acc, 0, 0, 0);
            acc = __builtin_amdgcn_mfma_f32_16x16x32_bf16(a1, bS1, acc, 0, 0, 0);
            sacc[mt] = acc;
        }

        // ---- online softmax: p = 2^(fma(S, L2E, -m*L2E)) ----
        float mx = sacc[0][0];
        #pragma unroll
        for (int mt = 0; mt < 4; ++mt)
            #pragma unroll
            for (int r = 0; r < 4; ++r) mx = fmaxf(mx, sacc[mt][r]);
        mx = fmaxf(mx, __shfl_xor(mx, 16));
        mx = fmaxf(mx, __shfl_xor(mx, 32));

        if (!__all(mx <= mrun)) {              // skip is exact when max stable
            float mnew = fmaxf(mrun, mx);
            float fs = ex2((mrun - mnew) * L2E);
            mrun = mnew;
            lrun *= fs;
            #pragma unroll
            for (int ct = 0; ct < 4; ++ct) {
                acc_o[ct][0] *= fs; acc_o[ct][1] *= fs;
                acc_o[ct][2] *= fs; acc_o[ct][3] *= fs;
            }
        }

        const float nm = -mrun * L2E;
        float s = 0.f;
        #pragma unroll
        for (int mt = 0; mt < 4; ++mt) {
            float p0 = ex2(__builtin_fmaf(sacc[mt][0], L2E, nm));
            float p1 = ex2(__builtin_fmaf(sacc[mt][1], L2E, nm));
            float p2 = ex2(__builtin_fmaf(sacc[mt][2], L2E, nm));
            float p3 = ex2(__builtin_fmaf(sacc[mt][3], L2E, nm));
            s += (p0 + p1) + (p2 + p3);
            uint2 pkv;
            pkv.x = pk2bf(p0, p1);
            pkv.y = pk2bf(p2, p3);
            *(uint2*)&PsW[ln * 72 + (mt << 4) + (g << 2)] = pkv;
        }
        s += __shfl_xor(s, 16);
        s += __shfl_xor(s, 32);
        lrun += s;

        // ---- PV: D[c][n] += v[c][m] * P[m][n] ----
        short8v bp0 = *(const short8v*)&PsW[ln * 72 + (g << 3)];
        short8v bp1 = *(const short8v*)&PsW[ln * 72 + 32 + (g << 3)];
        #pragma unroll
        for (int ct = 0; ct < 4; ++ct) {
            short8v a0 = *(const short8v*)&vS[((ct << 4) + ln) * 72 + (g << 3)];
            short8v a1 = *(const short8v*)&vS[((ct << 4) + ln) * 72 + 32 + (g << 3)];
            acc_o[ct] = __builtin_amdgcn_mfma_f32_16x16x32_bf16(a0, bp0, acc_o[ct], 0, 0, 0);
            acc_o[ct] = __builtin_amdgcn_mfma_f32_16x16x32_bf16(a1, bp1, acc_o[ct], 0, 0, 0);
        }
    }

    // ---- emit partial (m,l natural domain) ----
    __syncthreads();
    float* xp = (float*)(smem + 4608);         // [64 q][68 c]
    #pragma unroll
    for (int ct = 0; ct < 4; ++ct)
        #pragma unroll
        for (int r = 0; r < 4; ++r)
            xp[((w << 4) + ln) * 68 + (ct << 4) + (g << 2) + r] = acc_o[ct][r];
    if (g == 0) {
        mlpart[(size_t)part * 128 + (w << 4) + ln]      = mrun;
        mlpart[(size_t)part * 128 + 64 + (w << 4) + ln] = lrun;
    }
    __syncthreads();
    {
        int q = tid >> 2, c16 = (tid & 3) << 4;
        float* Ob = opart + (size_t)part * 4096 + q * 64 + c16;
        #pragma unroll
        for (int i = 0; i < 4; ++i)
            *(float4*)&Ob[i << 2] = *(const float4*)&xp[q * 68 + c16 + (i << 2)];
    }
}

// ---------------------------------------------------------------------------
// Kernel 3: merge 4 key-chunk partials + W2 + BN + ReLU + residual.
// ---------------------------------------------------------------------------
__global__ __launch_bounds__(256) void attn_merge(
    const float* __restrict__ opart, const float* __restrict__ mlpart,
    const float* __restrict__ W2,
    const float* __restrict__ gamma, const float* __restrict__ beta,
    const float* __restrict__ rmean, const float* __restrict__ rvar,
    const float* __restrict__ x, float* __restrict__ out)
{
    __shared__ __align__(16) short attL[64 * 72];
    __shared__ __align__(16) short w2s [64 * 72];
    __shared__ float wgt[4][64];
    __shared__ float linv[64];

    const int tid = threadIdx.x;
    const int w  = tid >> 6;
    const int l  = tid & 63;
    const int g  = l >> 4;
    const int ln = l & 15;

    const int b    = blockIdx.x >> 6;
    const int qblk = blockIdx.x & 63;
    const int n0   = qblk << 6;
    const int part0 = (b << 8) | qblk;

    if (tid < 64) {
        float m0 = mlpart[(size_t)(part0)        * 128 + tid];
        float m1 = mlpart[(size_t)(part0 + 64)   * 128 + tid];
        float m2 = mlpart[(size_t)(part0 + 128)  * 128 + tid];
        float m3 = mlpart[(size_t)(part0 + 192)  * 128 + tid];
        float l0 = mlpart[(size_t)(part0)        * 128 + 64 + tid];
        float l1 = mlpart[(size_t)(part0 + 64)   * 128 + 64 + tid];
        float l2 = mlpart[(size_t)(part0 + 128)  * 128 + 64 + tid];
        float l3 = mlpart[(size_t)(part0 + 192)  * 128 + 64 + tid];
        float mm = fmaxf(fmaxf(m0, m1), fmaxf(m2, m3));
        float w0 = ex2((m0 - mm) * L2E), w1 = ex2((m1 - mm) * L2E);
        float w2 = ex2((m2 - mm) * L2E), w3 = ex2((m3 - mm) * L2E);
        wgt[0][tid] = w0; wgt[1][tid] = w1; wgt[2][tid] = w2; wgt[3][tid] = w3;
        linv[tid] = 1.0f / (w0 * l0 + w1 * l1 + w2 * l2 + w3 * l3);
    }
    for (int i = tid; i < 1024; i += 256) {
        int r = i >> 4, c4 = (i & 15) << 2;
        float4 wv = *(const float4*)&W2[(r << 6) + c4];
        uint2 s4;
        s4.x = pk2bf(wv.x, wv.y);
        s4.y = pk2bf(wv.z, wv.w);
        *(uint2*)&w2s[r * 72 + c4] = s4;
    }
    __syncthreads();

    {
        int q = tid >> 2, c16 = (tid & 3) << 4;
        float a[16] = {};
        #pragma unroll
        for (int kc = 0; kc < 4; ++kc) {
            float wk = wgt[kc][q];
            const float* Ob = opart + (size_t)(part0 + (kc << 6)) * 4096 + q * 64 + c16;
            #pragma unroll
            for (int i = 0; i < 4; ++i) {
                float4 o4 = *(const float4*)&Ob[i << 2];
                a[(i << 2) + 0] += wk * o4.x;
                a[(i << 2) + 1] += wk * o4.y;
                a[(i << 2) + 2] += wk * o4.z;
                a[(i << 2) + 3] += wk * o4.w;
            }
        }
        float li = linv[q];
        #pragma unroll
        for (int i = 0; i < 4; ++i) {
            uint2 s4;
            s4.x = pk2bf(a[(i << 2) + 0] * li, a[(i << 2) + 1] * li);
            s4.y = pk2bf(a[(i << 2) + 2] * li, a[(i << 2) + 3] * li);
            *(uint2*)&attL[q * 72 + c16 + (i << 2)] = s4;
        }
    }
    __syncthreads();

    short8v bA0 = *(const short8v*)&attL[((w << 4) + ln) * 72 + (g << 3)];
    short8v bA1 = *(const short8v*)&attL[((w << 4) + ln) * 72 + 32 + (g << 3)];
    const int nq = n0 + (w << 4) + ln;
    #pragma unroll
    for (int ot = 0; ot < 4; ++ot) {
        short8v a0 = *(const short8v*)&w2s[((ot << 4) + ln) * 72 + (g << 3)];
        short8v a1 = *(const short8v*)&w2s[((ot << 4) + ln) * 72 + 32 + (g << 3)];
        floatx4 acc = (floatx4){0.f, 0.f, 0.f, 0.f};
        acc = __builtin_amdgcn_mfma_f32_16x16x32_bf16(a0, bA0, acc, 0, 0, 0);
        acc = __builtin_amdgcn_mfma_f32_16x16x32_bf16(a1, bA1, acc, 0, 0, 0);
        int o0 = (ot << 4) + (g << 2);
        float4 gm = *(const float4*)&gamma[o0];
        float4 bt = *(const float4*)&beta [o0];
        float4 rm = *(const float4*)&rmean[o0];
        float4 rv = *(const float4*)&rvar [o0];
        float gma[4] = {gm.x, gm.y, gm.z, gm.w};
        float bta[4] = {bt.x, bt.y, bt.z, bt.w};
        float rma[4] = {rm.x, rm.y, rm.z, rm.w};
        float rva[4] = {rv.x, rv.y, rv.z, rv.w};
        #pragma unroll
        for (int r = 0; r < 4; ++r) {
            float inv  = gma[r] * __frsqrt_rn(rva[r] + 1e-5f);
            float bias = bta[r] - rma[r] * inv;
            size_t ga = (((size_t)(b << 6) + o0 + r) << 12) + nq;
            out[ga] = fmaxf(acc[r] * inv + bias, 0.f) + x[ga];
        }
    }
}

// ---------------------------------------------------------------------------
extern "C" void kernel_launch(void* const* d_in, const int* in_sizes, int n_in,
                              void* d_out, int out_size, void* d_ws, size_t ws_size,
                              hipStream_t stream)
{
    const float* x     = (const float*)d_in[0];
    const float* Wk    = (const float*)d_in[1];
    const float* Wq    = (const float*)d_in[2];
    const float* Wv    = (const float*)d_in[3];
    const float* W2    = (const float*)d_in[4];
    const float* gamma = (const float*)d_in[5];
    const float* beta  = (const float*)d_in[6];
    const float* rmean = (const float*)d_in[7];
    const float* rvar  = (const float*)d_in[8];
    float* out = (float*)d_out;

    const size_t plane = (size_t)NB * NTOT * CH;    // 1M elements
    short* kT = (short*)d_ws;
    short* qT = kT + plane;
    short* vv = qT + plane;
    float* opart  = (float*)(vv + plane);           // 1024 x 4096 f32 = 16 MB
    float* mlpart = opart + (size_t)1024 * 4096;    // 1024 x 128  f32 = 0.5 MB

    qkv_proj    <<<dim3(512),  dim3(256), 0, stream>>>(x, Wk, Wq, Wv, kT, qT, vv);
    attn_partial<<<dim3(1024), dim3(256), 0, stream>>>(kT, qT, vv, opart, mlpart);
    attn_merge  <<<dim3(256),  dim3(256), 0, stream>>>(opart, mlpart, W2, gamma, beta,
                                                       rmean, rvar, x, out);
}

// Round 11
// 62.880 us; speedup vs baseline: 1.1017x; 1.1017x over previous
//
#include <hip/hip_runtime.h>

#define CH   64
#define NTOT 4096
#define NB   4
#define L2E  1.44269504088896340736f

typedef short  short4v  __attribute__((ext_vector_type(4)));
typedef short  short8v  __attribute__((ext_vector_type(8)));
typedef float  floatx4  __attribute__((ext_vector_type(4)));

static __device__ __forceinline__ unsigned pk2bf(float lo, float hi) {
    unsigned r;
    asm("v_cvt_pk_bf16_f32 %0, %1, %2" : "=v"(r) : "v"(lo), "v"(hi));
    return r;
}
static __device__ __forceinline__ float ex2(float x) {
    return __builtin_amdgcn_exp2f(x);
}
static __device__ __forceinline__ short f2bf(float f) {
    union { float f; unsigned u; } v; v.f = f;
    unsigned r = v.u + 0x7FFFu + ((v.u >> 16) & 1u);
    return (short)(r >> 16);
}
static __device__ __forceinline__ float bf2f(short s) {
    union { unsigned u; float f; } v; v.u = ((unsigned)(unsigned short)s) << 16;
    return v.f;
}

// ---------------------------------------------------------------------------
// Kernel 1: QKV projection via bf16 hi/lo-split MFMA (fp32-grade precision).
//   kT, qT : (B, N, C) bf16;  v : (B, C, N) bf16
// grid = B * 64 (64-position tiles), 256 threads = 4 waves (wave w: n-sub w)
// ---------------------------------------------------------------------------
__global__ __launch_bounds__(256) void qkv_mfma(
    const float* __restrict__ x,
    const float* __restrict__ Wk, const float* __restrict__ Wq,
    const float* __restrict__ Wv,
    short* __restrict__ kT, short* __restrict__ qT, short* __restrict__ vg)
{
    __shared__ __align__(16) short xhi[64 * 72];
    __shared__ __align__(16) short xlo[64 * 72];
    __shared__ __align__(16) short whi[64 * 72];
    __shared__ __align__(16) short wlo[64 * 72];

    const int tid = threadIdx.x;
    const int w = tid >> 6, l = tid & 63, g = l >> 4, ln = l & 15;
    const int b  = blockIdx.x >> 6;
    const int n0 = (blockIdx.x & 63) << 6;
    const float* xb = x + ((size_t)b << 18);

    // ---- stage xT hi/lo: [n][c] transposed from x (b,c,n) ----
    #pragma unroll
    for (int i = 0; i < 4; ++i) {
        int idx = tid + (i << 8);
        int c = idx >> 4, n4 = (idx & 15) << 2;
        float4 xv = *(const float4*)&xb[c * 4096 + n0 + n4];
        float xa[4] = {xv.x, xv.y, xv.z, xv.w};
        #pragma unroll
        for (int j = 0; j < 4; ++j) {
            short h = f2bf(xa[j]);
            xhi[(n4 + j) * 72 + c] = h;
            xlo[(n4 + j) * 72 + c] = f2bf(xa[j] - bf2f(h));
        }
    }

    const int wo = tid >> 2, wc = (tid & 3) << 4;
    // stage Wk for phase 0
    #pragma unroll
    for (int j2 = 0; j2 < 4; ++j2) {
        float4 a = *(const float4*)&Wk[wo * 64 + wc + (j2 << 2)];
        float aa[4] = {a.x, a.y, a.z, a.w};
        #pragma unroll
        for (int j = 0; j < 4; ++j) {
            short h = f2bf(aa[j]);
            whi[wo * 72 + wc + (j2 << 2) + j] = h;
            wlo[wo * 72 + wc + (j2 << 2) + j] = f2bf(aa[j] - bf2f(h));
        }
    }
    __syncthreads();

    // hoisted x fragments (rows 16w+ln)
    short8v xh0 = *(const short8v*)&xhi[((w << 4) + ln) * 72 + (g << 3)];
    short8v xh1 = *(const short8v*)&xhi[((w << 4) + ln) * 72 + 32 + (g << 3)];
    short8v xl0 = *(const short8v*)&xlo[((w << 4) + ln) * 72 + (g << 3)];
    short8v xl1 = *(const short8v*)&xlo[((w << 4) + ln) * 72 + 32 + (g << 3)];

    #pragma unroll
    for (int m = 0; m < 3; ++m) {
        if (m > 0) {   // restage weights
            const float* W = (m == 1) ? Wq : Wv;
            #pragma unroll
            for (int j2 = 0; j2 < 4; ++j2) {
                float4 a = *(const float4*)&W[wo * 64 + wc + (j2 << 2)];
                float aa[4] = {a.x, a.y, a.z, a.w};
                #pragma unroll
                for (int j = 0; j < 4; ++j) {
                    short h = f2bf(aa[j]);
                    whi[wo * 72 + wc + (j2 << 2) + j] = h;
                    wlo[wo * 72 + wc + (j2 << 2) + j] = f2bf(aa[j] - bf2f(h));
                }
            }
            __syncthreads();
        }

        #pragma unroll
        for (int ot = 0; ot < 4; ++ot) {
            short8v ah0 = *(const short8v*)&whi[((ot << 4) + ln) * 72 + (g << 3)];
            short8v ah1 = *(const short8v*)&whi[((ot << 4) + ln) * 72 + 32 + (g << 3)];
            short8v al0 = *(const short8v*)&wlo[((ot << 4) + ln) * 72 + (g << 3)];
            short8v al1 = *(const short8v*)&wlo[((ot << 4) + ln) * 72 + 32 + (g << 3)];
            floatx4 acc = (floatx4){0.f, 0.f, 0.f, 0.f};
            if (m < 2) {
                // D[o=16ot+4g+r][n=16w+ln] : A = W rows, B = x rows
                acc = __builtin_amdgcn_mfma_f32_16x16x32_bf16(ah0, xh0, acc, 0, 0, 0);
                acc = __builtin_amdgcn_mfma_f32_16x16x32_bf16(ah1, xh1, acc, 0, 0, 0);
                acc = __builtin_amdgcn_mfma_f32_16x16x32_bf16(al0, xh0, acc, 0, 0, 0);
                acc = __builtin_amdgcn_mfma_f32_16x16x32_bf16(al1, xh1, acc, 0, 0, 0);
                acc = __builtin_amdgcn_mfma_f32_16x16x32_bf16(ah0, xl0, acc, 0, 0, 0);
                acc = __builtin_amdgcn_mfma_f32_16x16x32_bf16(ah1, xl1, acc, 0, 0, 0);
                short* dst = ((m == 0) ? kT : qT) + ((size_t)b << 18);
                uint2 p;
                p.x = pk2bf(acc[0], acc[1]);
                p.y = pk2bf(acc[2], acc[3]);
                *(uint2*)&dst[(size_t)(n0 + (w << 4) + ln) * 64 + (ot << 4) + (g << 2)] = p;
            } else {
                // D[n=16w+4g+r][o=16ot+ln] : A = x rows, B = W rows
                acc = __builtin_amdgcn_mfma_f32_16x16x32_bf16(xh0, ah0, acc, 0, 0, 0);
                acc = __builtin_amdgcn_mfma_f32_16x16x32_bf16(xh1, ah1, acc, 0, 0, 0);
                acc = __builtin_amdgcn_mfma_f32_16x16x32_bf16(xl0, ah0, acc, 0, 0, 0);
                acc = __builtin_amdgcn_mfma_f32_16x16x32_bf16(xl1, ah1, acc, 0, 0, 0);
                acc = __builtin_amdgcn_mfma_f32_16x16x32_bf16(xh0, al0, acc, 0, 0, 0);
                acc = __builtin_amdgcn_mfma_f32_16x16x32_bf16(xh1, al1, acc, 0, 0, 0);
                short* dst = vg + ((size_t)b << 18);
                uint2 p;
                p.x = pk2bf(acc[0], acc[1]);
                p.y = pk2bf(acc[2], acc[3]);
                *(uint2*)&dst[(size_t)((ot << 4) + ln) * 4096 + n0 + (w << 4) + (g << 2)] = p;
            }
        }
        __syncthreads();   // weight tables free before restage
    }
}

// ---------------------------------------------------------------------------
// Kernel 2: flash-attention partial, 128-query blocks over a 1024-key chunk.
// grid = 512 blocks (4 kc x 4 b x 32 qblk), 256 threads = 4 waves x 32 queries.
// LDS 55.3 KB: kTs[128][72] | qS[64][72] | vS[64][72] | Ps[4][32][72]
// ---------------------------------------------------------------------------
__global__ __launch_bounds__(256) void attn_partial(
    const short* __restrict__ kT, const short* __restrict__ qT,
    const short* __restrict__ vg,
    float* __restrict__ opart, float* __restrict__ mlpart)
{
    __shared__ __align__(16) short smem[27648];   // 55296 B

    const int tid = threadIdx.x;
    const int w = tid >> 6, l = tid & 63, g = l >> 4, ln = l & 15;

    const int bid = blockIdx.x;
    const int xcd = bid & 7, grp = bid >> 3;       // grp 0..63
    const int bk  = (xcd << 1) | (grp >> 5);       // 0..15 = (b,kc)
    const int b   = bk >> 2, kc = bk & 3;
    const int qblk = grp & 31;
    const int n0   = qblk << 7;
    const int part = (((b << 2) | kc) << 5) | qblk;
    const int kbase = kc << 10;

    const short* kTb = kT + ((size_t)b << 18) + (size_t)n0 * 64;
    const short* qTb = qT + ((size_t)b << 18);
    const short* vb  = vg + ((size_t)b << 18);

    short* const kTs = smem;             // [128][72]
    short* const qS  = smem + 9216;      // [64][72]
    short* const vS  = smem + 13824;     // [64][72]
    short* const PsW = smem + 18432 + w * 2304;   // [32][72]

    // stage the block's 128 queries
    #pragma unroll
    for (int j = 0; j < 4; ++j) {
        int row = tid >> 1, c8 = ((tid & 1) << 5) + (j << 3);
        *(short8v*)&kTs[row * 72 + c8] = *(const short8v*)&kTb[row * 64 + c8];
    }
    __syncthreads();

    short8v bS0 = *(const short8v*)&kTs[((w << 5) + ln) * 72 + (g << 3)];
    short8v bS1 = *(const short8v*)&kTs[((w << 5) + ln) * 72 + 32 + (g << 3)];
    short8v bS2 = *(const short8v*)&kTs[((w << 5) + 16 + ln) * 72 + (g << 3)];
    short8v bS3 = *(const short8v*)&kTs[((w << 5) + 16 + ln) * 72 + 32 + (g << 3)];

    float mrun0 = -1e30f, lrun0 = 0.f;
    float mrun1 = -1e30f, lrun1 = 0.f;
    floatx4 acc0[4], acc1[4];
    #pragma unroll
    for (int ct = 0; ct < 4; ++ct) {
        acc0[ct] = (floatx4){0.f, 0.f, 0.f, 0.f};
        acc1[ct] = (floatx4){0.f, 0.f, 0.f, 0.f};
    }

    const int i0 = tid, i1 = tid + 256;

    short8v pf[4];
    pf[0] = *(const short8v*)&qTb[(size_t)(kbase + (i0 >> 3)) * 64 + ((i0 & 7) << 3)];
    pf[1] = *(const short8v*)&qTb[(size_t)(kbase + (i1 >> 3)) * 64 + ((i1 & 7) << 3)];
    pf[2] = *(const short8v*)&vb[(size_t)(i0 >> 3) * 4096 + kbase + ((i0 & 7) << 3)];
    pf[3] = *(const short8v*)&vb[(size_t)(i1 >> 3) * 4096 + kbase + ((i1 & 7) << 3)];

    for (int t = 0; t < 16; ++t) {
        __syncthreads();
        *(short8v*)&qS[(i0 >> 3) * 72 + ((i0 & 7) << 3)] = pf[0];
        *(short8v*)&qS[(i1 >> 3) * 72 + ((i1 & 7) << 3)] = pf[1];
        *(short8v*)&vS[(i0 >> 3) * 72 + ((i0 & 7) << 3)] = pf[2];
        *(short8v*)&vS[(i1 >> 3) * 72 + ((i1 & 7) << 3)] = pf[3];
        __syncthreads();
        if (t < 15) {
            int m1 = kbase + ((t + 1) << 6);
            pf[0] = *(const short8v*)&qTb[(size_t)(m1 + (i0 >> 3)) * 64 + ((i0 & 7) << 3)];
            pf[1] = *(const short8v*)&qTb[(size_t)(m1 + (i1 >> 3)) * 64 + ((i1 & 7) << 3)];
            pf[2] = *(const short8v*)&vb[(size_t)(i0 >> 3) * 4096 + m1 + ((i0 & 7) << 3)];
            pf[3] = *(const short8v*)&vb[(size_t)(i1 >> 3) * 4096 + m1 + ((i1 & 7) << 3)];
        }

        // ---- S^T tiles for both query groups (shared A-reads) ----
        floatx4 s0[4], s1[4];
        #pragma unroll
        for (int mt = 0; mt < 4; ++mt) {
            short8v a0 = *(const short8v*)&qS[((mt << 4) + ln) * 72 + (g << 3)];
            short8v a1 = *(const short8v*)&qS[((mt << 4) + ln) * 72 + 32 + (g << 3)];
            floatx4 acc = (floatx4){0.f, 0.f, 0.f, 0.f};
            acc = __builtin_amdgcn_mfma_f32_16x16x32_bf16(a0, bS0, acc, 0, 0, 0);
            acc = __builtin_amdgcn_mfma_f32_16x16x32_bf16(a1, bS1, acc, 0, 0, 0);
            s0[mt] = acc;
            acc = (floatx4){0.f, 0.f, 0.f, 0.f};
            acc = __builtin_amdgcn_mfma_f32_16x16x32_bf16(a0, bS2, acc, 0, 0, 0);
            acc = __builtin_amdgcn_mfma_f32_16x16x32_bf16(a1, bS3, acc, 0, 0, 0);
            s1[mt] = acc;
        }

        // ---- online softmax, query group 0 ----
        {
            float mx = s0[0][0];
            #pragma unroll
            for (int mt = 0; mt < 4; ++mt)
                #pragma unroll
                for (int r = 0; r < 4; ++r) mx = fmaxf(mx, s0[mt][r]);
            mx = fmaxf(mx, __shfl_xor(mx, 16));
            mx = fmaxf(mx, __shfl_xor(mx, 32));
            if (!__all(mx <= mrun0)) {
                float mnew = fmaxf(mrun0, mx);
                float fs = ex2((mrun0 - mnew) * L2E);
                mrun0 = mnew;
                lrun0 *= fs;
                #pragma unroll
                for (int ct = 0; ct < 4; ++ct) {
                    acc0[ct][0] *= fs; acc0[ct][1] *= fs;
                    acc0[ct][2] *= fs; acc0[ct][3] *= fs;
                }
            }
            const float nm = -mrun0 * L2E;
            float s = 0.f;
            #pragma unroll
            for (int mt = 0; mt < 4; ++mt) {
                float p0 = ex2(__builtin_fmaf(s0[mt][0], L2E, nm));
                float p1 = ex2(__builtin_fmaf(s0[mt][1], L2E, nm));
                float p2 = ex2(__builtin_fmaf(s0[mt][2], L2E, nm));
                float p3 = ex2(__builtin_fmaf(s0[mt][3], L2E, nm));
                s += (p0 + p1) + (p2 + p3);
                uint2 pkv;
                pkv.x = pk2bf(p0, p1);
                pkv.y = pk2bf(p2, p3);
                *(uint2*)&PsW[ln * 72 + (mt << 4) + (g << 2)] = pkv;
            }
            s += __shfl_xor(s, 16);
            s += __shfl_xor(s, 32);
            lrun0 += s;
        }
        // ---- online softmax, query group 1 ----
        {
            float mx = s1[0][0];
            #pragma unroll
            for (int mt = 0; mt < 4; ++mt)
                #pragma unroll
                for (int r = 0; r < 4; ++r) mx = fmaxf(mx, s1[mt][r]);
            mx = fmaxf(mx, __shfl_xor(mx, 16));
            mx = fmaxf(mx, __shfl_xor(mx, 32));
            if (!__all(mx <= mrun1)) {
                float mnew = fmaxf(mrun1, mx);
                float fs = ex2((mrun1 - mnew) * L2E);
                mrun1 = mnew;
                lrun1 *= fs;
                #pragma unroll
                for (int ct = 0; ct < 4; ++ct) {
                    acc1[ct][0] *= fs; acc1[ct][1] *= fs;
                    acc1[ct][2] *= fs; acc1[ct][3] *= fs;
                }
            }
            const float nm = -mrun1 * L2E;
            float s = 0.f;
            #pragma unroll
            for (int mt = 0; mt < 4; ++mt) {
                float p0 = ex2(__builtin_fmaf(s1[mt][0], L2E, nm));
                float p1 = ex2(__builtin_fmaf(s1[mt][1], L2E, nm));
                float p2 = ex2(__builtin_fmaf(s1[mt][2], L2E, nm));
                float p3 = ex2(__builtin_fmaf(s1[mt][3], L2E, nm));
                s += (p0 + p1) + (p2 + p3);
                uint2 pkv;
                pkv.x = pk2bf(p0, p1);
                pkv.y = pk2bf(p2, p3);
                *(uint2*)&PsW[(16 + ln) * 72 + (mt << 4) + (g << 2)] = pkv;
            }
            s += __shfl_xor(s, 16);
            s += __shfl_xor(s, 32);
            lrun1 += s;
        }

        // ---- PV for both groups (shared vS A-reads) ----
        short8v bp0 = *(const short8v*)&PsW[ln * 72 + (g << 3)];
        short8v bp1 = *(const short8v*)&PsW[ln * 72 + 32 + (g << 3)];
        short8v bp2 = *(const short8v*)&PsW[(16 + ln) * 72 + (g << 3)];
        short8v bp3 = *(const short8v*)&PsW[(16 + ln) * 72 + 32 + (g << 3)];
        #pragma unroll
        for (int ct = 0; ct < 4; ++ct) {
            short8v a0 = *(const short8v*)&vS[((ct << 4) + ln) * 72 + (g << 3)];
            short8v a1 = *(const short8v*)&vS[((ct << 4) + ln) * 72 + 32 + (g << 3)];
            acc0[ct] = __builtin_amdgcn_mfma_f32_16x16x32_bf16(a0, bp0, acc0[ct], 0, 0, 0);
            acc0[ct] = __builtin_amdgcn_mfma_f32_16x16x32_bf16(a1, bp1, acc0[ct], 0, 0, 0);
            acc1[ct] = __builtin_amdgcn_mfma_f32_16x16x32_bf16(a0, bp2, acc1[ct], 0, 0, 0);
            acc1[ct] = __builtin_amdgcn_mfma_f32_16x16x32_bf16(a1, bp3, acc1[ct], 0, 0, 0);
        }
    }

    // ---- emit partial ----
    __syncthreads();
    float* xp = (float*)(smem + 9216);     // [128][68]
    #pragma unroll
    for (int ct = 0; ct < 4; ++ct)
        #pragma unroll
        for (int r = 0; r < 4; ++r) {
            xp[((w << 5) + ln) * 68 + (ct << 4) + (g << 2) + r]      = acc0[ct][r];
            xp[((w << 5) + 16 + ln) * 68 + (ct << 4) + (g << 2) + r] = acc1[ct][r];
        }
    if (g == 0) {
        mlpart[(size_t)part * 256 + (w << 5) + ln]            = mrun0;
        mlpart[(size_t)part * 256 + (w << 5) + 16 + ln]       = mrun1;
        mlpart[(size_t)part * 256 + 128 + (w << 5) + ln]      = lrun0;
        mlpart[(size_t)part * 256 + 128 + (w << 5) + 16 + ln] = lrun1;
    }
    __syncthreads();
    {
        int q = tid >> 1, c32 = (tid & 1) << 5;
        float* Ob = opart + (size_t)part * 8192 + q * 64 + c32;
        const float* Xp = &xp[q * 68 + c32];
        #pragma unroll
        for (int j = 0; j < 8; ++j)
            *(float4*)&Ob[j << 2] = *(const float4*)&Xp[j << 2];
    }
}

// ---------------------------------------------------------------------------
// Kernel 3: merge 4 key-chunk partials + W2 + BN + ReLU + residual.
// grid = 4 b x 64 qblk64 = 256 blocks, 256 threads.
// ---------------------------------------------------------------------------
__global__ __launch_bounds__(256) void attn_merge(
    const float* __restrict__ opart, const float* __restrict__ mlpart,
    const float* __restrict__ W2,
    const float* __restrict__ gamma, const float* __restrict__ beta,
    const float* __restrict__ rmean, const float* __restrict__ rvar,
    const float* __restrict__ x, float* __restrict__ out)
{
    __shared__ __align__(16) short attL[64 * 72];
    __shared__ __align__(16) short w2s [64 * 72];
    __shared__ float wgt[4][64];
    __shared__ float linv[64];

    const int tid = threadIdx.x;
    const int w = tid >> 6, l = tid & 63, g = l >> 4, ln = l & 15;

    const int b      = blockIdx.x >> 6;
    const int qblk64 = blockIdx.x & 63;
    const int n0     = qblk64 << 6;
    const int qb128  = qblk64 >> 1;
    const int qoff   = (qblk64 & 1) << 6;

    if (tid < 64) {
        float mv[4], lv[4];
        #pragma unroll
        for (int kc = 0; kc < 4; ++kc) {
            int part = (((b << 2) | kc) << 5) | qb128;
            mv[kc] = mlpart[(size_t)part * 256 + qoff + tid];
            lv[kc] = mlpart[(size_t)part * 256 + 128 + qoff + tid];
        }
        float mm = fmaxf(fmaxf(mv[0], mv[1]), fmaxf(mv[2], mv[3]));
        float den = 0.f;
        #pragma unroll
        for (int kc = 0; kc < 4; ++kc) {
            float wk = ex2((mv[kc] - mm) * L2E);
            wgt[kc][tid] = wk;
            den += wk * lv[kc];
        }
        linv[tid] = 1.0f / den;
    }
    for (int i = tid; i < 1024; i += 256) {
        int r = i >> 4, c4 = (i & 15) << 2;
        float4 wv = *(const float4*)&W2[(r << 6) + c4];
        uint2 s4;
        s4.x = pk2bf(wv.x, wv.y);
        s4.y = pk2bf(wv.z, wv.w);
        *(uint2*)&w2s[r * 72 + c4] = s4;
    }
    __syncthreads();

    {
        int q = tid >> 2, c16 = (tid & 3) << 4;
        float a[16] = {};
        #pragma unroll
        for (int kc = 0; kc < 4; ++kc) {
            int part = (((b << 2) | kc) << 5) | qb128;
            float wk = wgt[kc][q];
            const float* Ob = opart + (size_t)part * 8192 + (qoff + q) * 64 + c16;
            #pragma unroll
            for (int i = 0; i < 4; ++i) {
                float4 o4 = *(const float4*)&Ob[i << 2];
                a[(i << 2) + 0] += wk * o4.x;
                a[(i << 2) + 1] += wk * o4.y;
                a[(i << 2) + 2] += wk * o4.z;
                a[(i << 2) + 3] += wk * o4.w;
            }
        }
        float li = linv[q];
        #pragma unroll
        for (int i = 0; i < 4; ++i) {
            uint2 s4;
            s4.x = pk2bf(a[(i << 2) + 0] * li, a[(i << 2) + 1] * li);
            s4.y = pk2bf(a[(i << 2) + 2] * li, a[(i << 2) + 3] * li);
            *(uint2*)&attL[q * 72 + c16 + (i << 2)] = s4;
        }
    }
    __syncthreads();

    short8v bA0 = *(const short8v*)&attL[((w << 4) + ln) * 72 + (g << 3)];
    short8v bA1 = *(const short8v*)&attL[((w << 4) + ln) * 72 + 32 + (g << 3)];
    const int nq = n0 + (w << 4) + ln;
    #pragma unroll
    for (int ot = 0; ot < 4; ++ot) {
        short8v a0 = *(const short8v*)&w2s[((ot << 4) + ln) * 72 + (g << 3)];
        short8v a1 = *(const short8v*)&w2s[((ot << 4) + ln) * 72 + 32 + (g << 3)];
        floatx4 acc = (floatx4){0.f, 0.f, 0.f, 0.f};
        acc = __builtin_amdgcn_mfma_f32_16x16x32_bf16(a0, bA0, acc, 0, 0, 0);
        acc = __builtin_amdgcn_mfma_f32_16x16x32_bf16(a1, bA1, acc, 0, 0, 0);
        int o0 = (ot << 4) + (g << 2);
        float4 gm = *(const float4*)&gamma[o0];
        float4 bt = *(const float4*)&beta [o0];
        float4 rm = *(const float4*)&rmean[o0];
        float4 rv = *(const float4*)&rvar [o0];
        float gma[4] = {gm.x, gm.y, gm.z, gm.w};
        float bta[4] = {bt.x, bt.y, bt.z, bt.w};
        float rma[4] = {rm.x, rm.y, rm.z, rm.w};
        float rva[4] = {rv.x, rv.y, rv.z, rv.w};
        #pragma unroll
        for (int r = 0; r < 4; ++r) {
            float inv  = gma[r] * __frsqrt_rn(rva[r] + 1e-5f);
            float bias = bta[r] - rma[r] * inv;
            size_t ga = (((size_t)(b << 6) + o0 + r) << 12) + nq;
            out[ga] = fmaxf(acc[r] * inv + bias, 0.f) + x[ga];
        }
    }
}

// ---------------------------------------------------------------------------
extern "C" void kernel_launch(void* const* d_in, const int* in_sizes, int n_in,
                              void* d_out, int out_size, void* d_ws, size_t ws_size,
                              hipStream_t stream)
{
    const float* x     = (const float*)d_in[0];
    const float* Wk    = (const float*)d_in[1];
    const float* Wq    = (const float*)d_in[2];
    const float* Wv    = (const float*)d_in[3];
    const float* W2    = (const float*)d_in[4];
    const float* gamma = (const float*)d_in[5];
    const float* beta  = (const float*)d_in[6];
    const float* rmean = (const float*)d_in[7];
    const float* rvar  = (const float*)d_in[8];
    float* out = (float*)d_out;

    const size_t plane = (size_t)NB * NTOT * CH;    // 1M elements
    short* kT = (short*)d_ws;
    short* qT = kT + plane;
    short* vv = qT + plane;
    float* opart  = (float*)(vv + plane);           // 512 x 8192 f32 = 16 MB
    float* mlpart = opart + (size_t)512 * 8192;     // 512 x 256  f32 = 0.5 MB

    qkv_mfma    <<<dim3(256), dim3(256), 0, stream>>>(x, Wk, Wq, Wv, kT, qT, vv);
    attn_partial<<<dim3(512), dim3(256), 0, stream>>>(kT, qT, vv, opart, mlpart);
    attn_merge  <<<dim3(256), dim3(256), 0, stream>>>(opart, mlpart, W2, gamma, beta,
                                                      rmean, rvar, x, out);
}